// Round 5
// baseline (828.203 us; speedup 1.0000x reference)
//
#include <hip/hip_runtime.h>
#include <hip/hip_bf16.h>
#include <stdint.h>

typedef __attribute__((ext_vector_type(8))) short bf16x8;
typedef __attribute__((ext_vector_type(4))) float f32x4;
typedef unsigned short u16;

#define M_ROWS 16384
#define N_COLS 4096
#define K_DIM  2048
#define TOPK   16
#define KSEL   24
#define CAP    32
#define INV_T  5.0f

#define BM2 256
#define BN2 256
#define BK2 64

// ---- async global->LDS 16B copy -------------------------------------------
__device__ __forceinline__ void async_cp16(const void* g, void* l) {
  __builtin_amdgcn_global_load_lds((const __attribute__((address_space(1))) uint32_t*)g,
                                   (__attribute__((address_space(3))) uint32_t*)l,
                                   16, 0, 0);
}

__device__ __forceinline__ u16 f2bf(float f) {
  __hip_bfloat16 h = __float2bfloat16(f);
  return *reinterpret_cast<u16*>(&h);
}
__device__ __forceinline__ uint2 pack4(float4 v) {
  uint2 r;
  r.x = (uint32_t)f2bf(v.x) | ((uint32_t)f2bf(v.y) << 16);
  r.y = (uint32_t)f2bf(v.z) | ((uint32_t)f2bf(v.w) << 16);
  return r;
}

// ---- prep: per-row inv-norm of x + bf16 cast (unnormalized) ---------------
__global__ __launch_bounds__(256) void prep_x_kernel(
    const float* __restrict__ x, u16* __restrict__ xh, float* __restrict__ invn) {
  const int row = blockIdx.x;
  const int t = threadIdx.x;
  const float4* xr = reinterpret_cast<const float4*>(x + (size_t)row * K_DIM);
  float4 v0 = xr[t];
  float4 v1 = xr[256 + t];
  float s = v0.x*v0.x + v0.y*v0.y + v0.z*v0.z + v0.w*v0.w
          + v1.x*v1.x + v1.y*v1.y + v1.z*v1.z + v1.w*v1.w;
  #pragma unroll
  for (int off = 1; off < 64; off <<= 1) s += __shfl_xor(s, off);
  __shared__ float ws4[4];
  if ((t & 63) == 0) ws4[t >> 6] = s;
  __syncthreads();
  if (t == 0) {
    float tot = ws4[0] + ws4[1] + ws4[2] + ws4[3];
    invn[row] = 1.0f / fmaxf(sqrtf(tot), 1e-12f);
  }
  uint2* xo = reinterpret_cast<uint2*>(xh + (size_t)row * K_DIM);
  xo[t] = pack4(v0);
  xo[256 + t] = pack4(v1);
}

// ---- prep: protos fp32 -> bf16 --------------------------------------------
__global__ __launch_bounds__(256) void prep_p_kernel(
    const float* __restrict__ p, u16* __restrict__ ph) {
  const int row = blockIdx.x;
  const int t = threadIdx.x;
  const float4* pr = reinterpret_cast<const float4*>(p + (size_t)row * K_DIM);
  uint2* po = reinterpret_cast<uint2*>(ph + (size_t)row * K_DIM);
  po[t] = pack4(pr[t]);
  po[256 + t] = pack4(pr[256 + t]);
}

// ---- staging helper: one 256x64 bf16 tile half-pair (A or B), 4 chunks ----
__device__ __forceinline__ void stage_tile(
    const char* Abase, const char* Bbase, u16* sAbuf, u16* sBbuf,
    const int* srow, const int* soff, int t, int kbyte) {
  #pragma unroll
  for (int c = 0; c < 4; ++c) {
    async_cp16(Abase + (size_t)srow[c] * (K_DIM * 2) + kbyte + soff[c],
               (char*)sAbuf + (c * 512 + t) * 16);
  }
  #pragma unroll
  for (int c = 0; c < 4; ++c) {
    async_cp16(Bbase + (size_t)srow[c] * (K_DIM * 2) + kbyte + soff[c],
               (char*)sBbuf + (c * 512 + t) * 16);
  }
}

// ---- bf16 GEMM 256x256 tile, 8 waves, dbuf LDS, 1 barrier / K-tile --------
// sims[m][n] = sum_k A[m][k]*B[n][k]  (B^T layout). Stage(t+1) issued BEFORE
// compute(t); single __syncthreads() per K-tile orders both LDS hazards
// (drain of stage(t+1) loads, and reads-of-t before stage(t+2) overwrite).
__global__ __launch_bounds__(512, 2) void gemm_bf16_256(
    const u16* __restrict__ A, const u16* __restrict__ B, float* __restrict__ C) {
  __shared__ __align__(16) u16 sA[2][BM2 * BK2];   // 2 x 32 KB
  __shared__ __align__(16) u16 sB[2][BN2 * BK2];   // 2 x 32 KB
  const int t = threadIdx.x;       // 0..511
  const int lane = t & 63;
  const int wid = t >> 6;          // 0..7
  const int wm = wid >> 2;         // 0..1  (M half)
  const int wn = wid & 3;          // 0..3  (N quarter)
  const int tm0 = blockIdx.y * BM2;
  const int tn0 = blockIdx.x * BN2;
  const int lr = lane & 15;
  const int hi = lane >> 4;

  f32x4 acc[8][4];
  #pragma unroll
  for (int i = 0; i < 8; ++i)
    #pragma unroll
    for (int j = 0; j < 4; ++j)
      acc[i][j] = (f32x4){0.f, 0.f, 0.f, 0.f};

  // staging source offsets (pre-swizzled global source, linear LDS dest)
  int srow[4], soff[4];
  #pragma unroll
  for (int c = 0; c < 4; ++c) {
    int idx = c * 512 + t;          // 16B-chunk index in [0,2048)
    srow[c] = idx >> 3;             // tile row 0..255
    soff[c] = ((idx & 7) << 4) ^ ((srow[c] & 7) << 4);
  }
  const char* Abase = (const char*)(A + (size_t)tm0 * K_DIM);
  const char* Bbase = (const char*)(B + (size_t)tn0 * K_DIM);

  stage_tile(Abase, Bbase, sA[0], sB[0], srow, soff, t, 0);
  __syncthreads();

  for (int kt = 0; kt < K_DIM / BK2; ++kt) {
    if (kt < K_DIM / BK2 - 1)
      stage_tile(Abase, Bbase, sA[(kt + 1) & 1], sB[(kt + 1) & 1],
                 srow, soff, t, (kt + 1) * (BK2 * 2));
    const char* cA = (const char*)sA[kt & 1];
    const char* cB = (const char*)sB[kt & 1];
    #pragma unroll
    for (int p = 0; p < 4; ++p) {
      const int i0 = (p & 1) * 4;
      const int j0 = (p >> 1) * 2;
      bf16x8 af[4][2], bq[2][2];
      #pragma unroll
      for (int ii = 0; ii < 4; ++ii) {
        #pragma unroll
        for (int kh = 0; kh < 2; ++kh) {
          int row = wm * 128 + (i0 + ii) * 16 + lr;
          int cb = (kh * 64 + hi * 16) ^ ((row & 7) << 4);
          af[ii][kh] = *reinterpret_cast<const bf16x8*>(cA + row * 128 + cb);
        }
      }
      #pragma unroll
      for (int jj = 0; jj < 2; ++jj) {
        #pragma unroll
        for (int kh = 0; kh < 2; ++kh) {
          int row = wn * 64 + (j0 + jj) * 16 + lr;
          int cb = (kh * 64 + hi * 16) ^ ((row & 7) << 4);
          bq[jj][kh] = *reinterpret_cast<const bf16x8*>(cB + row * 128 + cb);
        }
      }
      __builtin_amdgcn_s_setprio(1);
      #pragma unroll
      for (int ii = 0; ii < 4; ++ii)
        #pragma unroll
        for (int jj = 0; jj < 2; ++jj)
          #pragma unroll
          for (int kh = 0; kh < 2; ++kh)
            acc[i0 + ii][j0 + jj] = __builtin_amdgcn_mfma_f32_16x16x32_bf16(
                af[ii][kh], bq[jj][kh], acc[i0 + ii][j0 + jj], 0, 0, 0);
      __builtin_amdgcn_s_setprio(0);
    }
    __syncthreads();
  }

  // C write: col = lane&15, row = (lane>>4)*4 + reg  (m89-verified layout)
  #pragma unroll
  for (int i = 0; i < 8; ++i) {
    #pragma unroll
    for (int j = 0; j < 4; ++j) {
      int colg = tn0 + wn * 64 + j * 16 + lr;
      int rowb = tm0 + wm * 128 + i * 16 + (hi << 2);
      #pragma unroll
      for (int r = 0; r < 4; ++r) {
        __builtin_nontemporal_store(acc[i][j][r], &C[(size_t)(rowb + r) * N_COLS + colg]);
      }
    }
  }
}

// ---- per-row: 4-pass 32-bit radix select -> exact rescore -> top-16 -------
__global__ __launch_bounds__(256) void topk_kernel(
    const float* __restrict__ x, const float* __restrict__ protos,
    const float* __restrict__ invn, float* __restrict__ out) {
  const int row = blockIdx.x;
  const int t = threadIdx.x;
  const int lane = t & 63;
  const int wid = t >> 6;

  __shared__ __align__(16) f32x4 lx[512];       // x row, 8 KB
  __shared__ int hist[4][257];                  // padded -> distinct banks
  __shared__ int selInfo[2];
  __shared__ int   cand[CAP];
  __shared__ float cexact[CAP];
  __shared__ int   spos[TOPK];
  __shared__ float sval[TOPK];
  __shared__ int cnt, csel;

  float* orow = out + (size_t)row * N_COLS;
  const f32x4* orow4 = reinterpret_cast<const f32x4*>(orow);

  // load approx sims (nt, streaming) -> 32-bit order-preserving keys
  uint32_t key[16];
  #pragma unroll
  for (int i = 0; i < 4; ++i) {
    f32x4 v = __builtin_nontemporal_load(orow4 + i * 256 + t);
    #pragma unroll
    for (int c = 0; c < 4; ++c) {
      uint32_t u = __float_as_uint(v[c]);
      key[i * 4 + c] = (u & 0x80000000u) ? ~u : (u | 0x80000000u);
    }
  }

  // stage x row into LDS (nt, streaming)
  const f32x4* xr = reinterpret_cast<const f32x4*>(x + (size_t)row * K_DIM);
  lx[t] = __builtin_nontemporal_load(xr + t);
  lx[256 + t] = __builtin_nontemporal_load(xr + 256 + t);
  if (t == 0) cnt = 0;

  // --- 4-pass radix select: exact KSEL-th largest 32-bit key ---
  uint32_t prefix = 0;
  int K_rem = KSEL;
  #pragma unroll
  for (int pass = 0; pass < 4; ++pass) {
    const int shift = 24 - pass * 8;
    hist[0][t] = 0; hist[1][t] = 0; hist[2][t] = 0; hist[3][t] = 0;
    __syncthreads();
    const uint32_t prefMask = (pass == 0) ? 0u : (0xFFFFFFFFu << (shift + 8));
    #pragma unroll
    for (int j = 0; j < 16; ++j) {
      if ((key[j] & prefMask) == prefix)
        atomicAdd(&hist[wid][(key[j] >> shift) & 255], 1);
    }
    __syncthreads();
    if (wid == 0) {
      const int b0 = lane << 2;
      int h0 = hist[0][b0]     + hist[1][b0]     + hist[2][b0]     + hist[3][b0];
      int h1 = hist[0][b0 + 1] + hist[1][b0 + 1] + hist[2][b0 + 1] + hist[3][b0 + 1];
      int h2 = hist[0][b0 + 2] + hist[1][b0 + 2] + hist[2][b0 + 2] + hist[3][b0 + 2];
      int h3 = hist[0][b0 + 3] + hist[1][b0 + 3] + hist[2][b0 + 3] + hist[3][b0 + 3];
      int loc = h0 + h1 + h2 + h3;
      int s = loc;
      #pragma unroll
      for (int off = 1; off < 64; off <<= 1) {
        int o = __shfl_down(s, off);
        if (lane + off < 64) s += o;
      }
      const int tail = s - loc;
      int s3 = tail + h3;
      int s2 = s3 + h2;
      int s1 = s2 + h1;
      int s0 = s1 + h0;
      int ge[4] = {s0, s1, s2, s3};
      int hh[4] = {h0, h1, h2, h3};
      #pragma unroll
      for (int k = 0; k < 4; ++k) {
        int gt = ge[k] - hh[k];
        if (gt < K_rem && ge[k] >= K_rem) {
          selInfo[0] = b0 + k;
          selInfo[1] = K_rem - gt;
        }
      }
    }
    __syncthreads();
    prefix |= ((uint32_t)selInfo[0]) << shift;
    K_rem = selInfo[1];
  }
  const uint32_t T = prefix;

  // --- compact candidates: keys > T, then ties == T (cap CAP) ---
  #pragma unroll
  for (int j = 0; j < 16; ++j) {
    if (key[j] > T) {
      int s = atomicAdd(&cnt, 1);
      cand[s] = ((j >> 2) << 10) + (t << 2) + (j & 3);
    }
  }
  __syncthreads();
  #pragma unroll
  for (int j = 0; j < 16; ++j) {
    if (key[j] == T) {
      int s = atomicAdd(&cnt, 1);
      if (s < CAP) cand[s] = ((j >> 2) << 10) + (t << 2) + (j & 3);
    }
  }
  __syncthreads();
  const int c = min(cnt, CAP);

  // --- exact fp32 rescore (arithmetic order identical to R1/R2/R4) ---
  const float inv = invn[row];
  for (int ci = wid; ci < c; ci += 4) {
    int pidx = cand[ci];
    const f32x4* pr = reinterpret_cast<const f32x4*>(protos + (size_t)pidx * K_DIM);
    float s = 0.f;
    #pragma unroll
    for (int i = 0; i < 8; ++i) {
      f32x4 pv = pr[i * 64 + lane];
      f32x4 xv = lx[i * 64 + lane];
      s = fmaf(pv.x, xv.x, s);
      s = fmaf(pv.y, xv.y, s);
      s = fmaf(pv.z, xv.z, s);
      s = fmaf(pv.w, xv.w, s);
    }
    #pragma unroll
    for (int off = 1; off < 64; off <<= 1) s += __shfl_xor(s, off);
    if (lane == 0) cexact[ci] = s * inv;
  }
  __syncthreads();

  // --- exact top-16 + softmax (wave 0), publish (pos,val) pairs ---
  if (wid == 0) {
    float v = (lane < c) ? cexact[lane] : -3.0e38f;
    int pos = (lane < c) ? cand[lane] : 0x7fffffff;
    int rank = 0;
    for (int j = 0; j < c; ++j) {
      float vj = __shfl(v, j);
      int   pj = __shfl(pos, j);
      if (lane < c && j != lane)
        if (vj > v || (vj == v && pj < pos)) rank++;
    }
    bool sel = (lane < c) && (rank < TOPK);
    float vm = sel ? v : -3.0e38f;
    #pragma unroll
    for (int off = 1; off < 64; off <<= 1) vm = fmaxf(vm, __shfl_xor(vm, off));
    float e = sel ? expf((v - vm) * INV_T) : 0.f;
    float se = e;
    #pragma unroll
    for (int off = 1; off < 64; off <<= 1) se += __shfl_xor(se, off);
    unsigned long long bal = __ballot(sel);
    int slot = __popcll(bal & ((1ull << lane) - 1ull));
    if (sel) { spos[slot] = pos; sval[slot] = e / se; }
    if (lane == 0) csel = (int)__popcll(bal);
  }
  __syncthreads();

  // --- single streaming write: zeros with the selected values merged in ---
  const int ns = csel;
  f32x4* orow4w = reinterpret_cast<f32x4*>(orow);
  #pragma unroll
  for (int i = 0; i < 4; ++i) {
    f32x4 o = (f32x4){0.f, 0.f, 0.f, 0.f};
    for (int s = 0; s < ns; ++s) {
      int p = spos[s];
      if ((p >> 10) == i && ((p >> 2) & 255) == t) o[p & 3] = sval[s];
    }
    __builtin_nontemporal_store(o, orow4w + i * 256 + t);
  }
}

extern "C" void kernel_launch(void* const* d_in, const int* in_sizes, int n_in,
                              void* d_out, int out_size, void* d_ws, size_t ws_size,
                              hipStream_t stream) {
  const float* x = (const float*)d_in[0];
  const float* protos = (const float*)d_in[1];
  float* out = (float*)d_out;

  char* ws = (char*)d_ws;
  u16* xh = (u16*)ws;                                        // 64 MB
  u16* ph = (u16*)(ws + (size_t)M_ROWS * K_DIM * 2);         // 16 MB
  float* invn = (float*)(ws + (size_t)(M_ROWS + N_COLS) * K_DIM * 2); // 64 KB

  prep_x_kernel<<<M_ROWS, 256, 0, stream>>>(x, xh, invn);
  prep_p_kernel<<<N_COLS, 256, 0, stream>>>(protos, ph);

  dim3 gg(N_COLS / BN2, M_ROWS / BM2);   // (16, 64)
  gemm_bf16_256<<<gg, 512, 0, stream>>>(xh, ph, out);

  topk_kernel<<<M_ROWS, 256, 0, stream>>>(x, protos, invn, out);
}